// Round 9
// baseline (481.750 us; speedup 1.0000x reference)
//
#include <hip/hip_runtime.h>
#include <hip/hip_cooperative_groups.h>
#include <cfloat>

namespace cg = cooperative_groups;

typedef unsigned short u16;
typedef unsigned int u32;
typedef __bf16 v8bf16 __attribute__((ext_vector_type(8)));
typedef float v4f32 __attribute__((ext_vector_type(4)));
typedef float v16f32 __attribute__((ext_vector_type(16)));

#define MPAD 4224            // 4097 keys padded to 66*64
// sqrt(1/8) * sqrt(log2(e)) : folds head-scale AND base-2 softmax into q and k
#define QKS 0.42466090f
#define GRPS 1024            // waves per split: (16 bh) * (16 qt) * (4 w)

__device__ __forceinline__ u16 f2bf(float f) {
  union { float f; u32 u; } v; v.f = f;
  u32 u = v.u;
  u32 r = (u + 0x7FFFu + ((u >> 16) & 1u)) >> 16;
  return (u16)r;
}

// pack two f32 -> one u32 holding (bf16(hi)<<16)|bf16(lo), truncating
__device__ __forceinline__ u32 pkbf(float lo, float hi) {
  union { float f; u32 u; } a, c;
  a.f = lo; c.f = hi;
  return __builtin_amdgcn_perm(c.u, a.u, 0x07060302);
}

__device__ __forceinline__ float asf(u32 u) {
  union { u32 u; float f; } v; v.u = u; return v.f;
}

// exp2 + row-sum + bf16 pack for one q-group (both kc halves).
// Half-wave exchange via v_permlane32_swap_b32 (R1/R8-proven).
__device__ __forceinline__ void exppack2(v16f32& sA, v16f32& sB, float& lst,
                                         v8bf16 pf[4]) {
  float rsum = 0.f;
#pragma unroll
  for (int i = 0; i < 16; i++) { float p = __builtin_amdgcn_exp2f(sA[i]); sA[i] = p; rsum += p; }
#pragma unroll
  for (int i = 0; i < 16; i++) { float p = __builtin_amdgcn_exp2f(sB[i]); sB[i] = p; rsum += p; }
  float a2 = rsum, b2 = rsum;
  asm("v_permlane32_swap_b32 %0, %1" : "+v"(a2), "+v"(b2));
  lst += a2 + b2;   // own + partner (lane^32)
#pragma unroll
  for (int kc = 0; kc < 2; kc++) {
    v16f32& s = kc ? sB : sA;
#pragma unroll
    for (int s16 = 0; s16 < 2; s16++) {
      u32 w0 = pkbf(s[s16 * 8 + 0], s[s16 * 8 + 1]);
      u32 w1 = pkbf(s[s16 * 8 + 2], s[s16 * 8 + 3]);
      u32 w2 = pkbf(s[s16 * 8 + 4], s[s16 * 8 + 5]);
      u32 w3 = pkbf(s[s16 * 8 + 6], s[s16 * 8 + 7]);
      asm("v_permlane32_swap_b32 %0, %1" : "+v"(w0), "+v"(w2));
      asm("v_permlane32_swap_b32 %0, %1" : "+v"(w1), "+v"(w3));
      union { u32 u[4]; v8bf16 v; } pu;
      pu.u[0] = w0; pu.u[1] = w1; pu.u[2] = w2; pu.u[3] = w3;
      pf[kc * 2 + s16] = pu.v;
    }
  }
}

// ================= prep_all: 4 independent prep stages in ONE launch ===============
// blocks [0,33): mask bias  | [33,1057): W transposes | [1057,7201): ln(x)+cast(ctx)
// | [7201,7217): KVt null-row/pad-tile fill.  All stages mutually independent.
__global__ __launch_bounds__(256) void prep_all(
    const void* __restrict__ mask, float* __restrict__ mp,
    const float* __restrict__ Wq, const float* __restrict__ Wkv,
    const float* __restrict__ Wo, u16* __restrict__ WqT,
    u16* __restrict__ WkvT, u16* __restrict__ WoT,
    const float* __restrict__ x, const float* __restrict__ g,
    u16* __restrict__ xn, const float4* __restrict__ ctx, u16* __restrict__ cb,
    const float* __restrict__ nullkv, u16* __restrict__ KVt) {
  int bb = blockIdx.x;
  int tid = threadIdx.x;
  if (bb < 33) {
    // ---- mask bias build (dtype detect folded in: per-block 8KB scan)
    __shared__ int sflag;
    if (tid == 0) sflag = 0;
    __syncthreads();
    const unsigned char* mb = (const unsigned char*)mask;
    int loc = 0;
#pragma unroll
    for (int k = 0; k < 32; k++) {
      int i = tid * 32 + k;
      if ((i & 3) && mb[i]) loc = 1;
    }
    if (loc) sflag = 1;
    __syncthreads();
    int isbyte = sflag;
    int i = bb * 256 + tid;
    if (i >= 2 * MPAD) return;
    int b = i / MPAD, p = i - b * MPAD;
    float v;
    if (p == 0) v = 0.f;
    else if (p <= 4096) {
      int j = b * 4096 + (p - 1);
      int on = isbyte ? (((const unsigned char*)mask)[j] != 0)
                      : (((const int*)mask)[j] != 0);
      v = on ? 0.f : -1e38f;
    } else v = -1e38f;
    mp[i] = v;
  } else if (bb < 1057) {
    // ---- fused transpose of Wq/Wkv/Wo fp32 [K][N] -> bf16 [N][K]
    __shared__ float tile[32][33];
    int t = bb - 33;
    const float* in; u16* out; int N; float scale; int base;
    if (t < 256)      { in = Wq;  out = WqT;  N = 512;  scale = QKS; base = t; }
    else if (t < 768) { in = Wkv; out = WkvT; N = 1024; scale = 1.f; base = t - 256; }
    else              { in = Wo;  out = WoT;  N = 512;  scale = 1.f; base = t - 768; }
    const int K = 512;
    int ntiles = N >> 5;
    int bx = base % ntiles, by = base / ntiles;
    int n0 = bx * 32, k0 = by * 32;
    int c = tid & 31, r8 = tid >> 5;
#pragma unroll
    for (int i = 0; i < 4; i++) {
      int r = r8 + i * 8;
      tile[r][c] = in[(size_t)(k0 + r) * N + n0 + c];
    }
    __syncthreads();
#pragma unroll
    for (int i = 0; i < 4; i++) {
      int r = r8 + i * 8;
      out[(size_t)(n0 + r) * K + k0 + c] = f2bf(tile[c][r] * scale);
    }
  } else if (bb < 7201) {
    int local = bb - 1057;
    if (local < 2048) {
      // ---- layernorm(x) row(512) -> bf16
      int lane = tid & 63, w = tid >> 6;
      int row = local * 4 + w;
      const float* p = x + (size_t)row * 512 + lane * 8;
      float4 f0 = *(const float4*)p;
      float4 f1 = *(const float4*)(p + 4);
      float v[8] = {f0.x, f0.y, f0.z, f0.w, f1.x, f1.y, f1.z, f1.w};
      float sum = 0.f, sq = 0.f;
#pragma unroll
      for (int i = 0; i < 8; i++) { sum += v[i]; sq += v[i] * v[i]; }
#pragma unroll
      for (int m = 1; m < 64; m <<= 1) { sum += __shfl_xor(sum, m); sq += __shfl_xor(sq, m); }
      float mean = sum * (1.f / 512.f);
      float var = sq * (1.f / 512.f) - mean * mean;
      float rstd = rsqrtf(var + 1e-5f);
      const float* gp = g + lane * 8;
      u16 o[8];
#pragma unroll
      for (int i = 0; i < 8; i++) o[i] = f2bf((v[i] - mean) * rstd * gp[i]);
      *(uint4*)&xn[(size_t)row * 512 + lane * 8] = *(uint4*)o;
    } else {
      // ---- cast context fp32 -> bf16
      int i = (local - 2048) * 256 + tid;
      float4 f = ctx[i];
      u16 o[4] = {f2bf(f.x), f2bf(f.y), f2bf(f.z), f2bf(f.w)};
      *(uint2*)&cb[(size_t)i * 4] = *(uint2*)o;
    }
  } else {
    // ---- KVt: zero pad tiles 64/65, write null row kk=0
    int bh = bb - 7201;
    size_t tb64 = ((size_t)bh * 66 + 64) * 8192;
    uint4 z = make_uint4(0, 0, 0, 0);
    for (int i = tid; i < 2048; i += 256)
      *(uint4*)&KVt[tb64 + (size_t)i * 8] = z;
    size_t tb0 = (size_t)bh * 66 * 8192;
    if (tid < 64) {
      int d = tid;
      KVt[tb0 + (size_t)(d >> 3) * 512 + (d & 7)] = f2bf(nullkv[d] * QKS);
      KVt[tb0 + 4096 + (size_t)d * 8] = f2bf(nullkv[64 + d]);
    }
  }
}

// ---------------- bf16 MFMA GEMM core: C[M x N] = A[M x 512] * Bt[N x 512]^T -------
// m97-structure: 128x128 tile, 256 thr (4 waves as 2x2, each 64x64, 4x4 acc)
// mode 0: out bf16 row-major [M][512]; mode 1: scatter to KVt frag-layout
__device__ __forceinline__ void gemm_core(const u16* __restrict__ A,
    const u16* __restrict__ Bt, u16* __restrict__ outb,
    u16* __restrict__ KVt, int Ncols, int mode, int bidx,
    u16* As /*128*32*/, u16* Bs /*128*32*/) {
  int tiles_n = Ncols >> 7;
  int n0 = (bidx % tiles_n) * 128;
  int m0 = (bidx / tiles_n) * 128;
  int tid = threadIdx.x;
  int lane = tid & 63, w = tid >> 6, quad = lane >> 4, l15 = lane & 15;
  int wr = w >> 1, wc = w & 1;
  int srow = tid >> 2, scol = (tid & 3) * 8;
  v4f32 acc[4][4];
#pragma unroll
  for (int i = 0; i < 4; i++)
#pragma unroll
    for (int j = 0; j < 4; j++) acc[i][j] = (v4f32){0.f, 0.f, 0.f, 0.f};

  for (int k0 = 0; k0 < 512; k0 += 32) {
    __syncthreads();
    __builtin_amdgcn_global_load_lds((const u32*)&A[(size_t)(m0 + srow) * 512 + k0 + scol],
                                     (u32*)&As[tid * 8], 16, 0, 0);
    __builtin_amdgcn_global_load_lds((const u32*)&A[(size_t)(m0 + 64 + srow) * 512 + k0 + scol],
                                     (u32*)&As[64 * 32 + tid * 8], 16, 0, 0);
    __builtin_amdgcn_global_load_lds((const u32*)&Bt[(size_t)(n0 + srow) * 512 + k0 + scol],
                                     (u32*)&Bs[tid * 8], 16, 0, 0);
    __builtin_amdgcn_global_load_lds((const u32*)&Bt[(size_t)(n0 + 64 + srow) * 512 + k0 + scol],
                                     (u32*)&Bs[64 * 32 + tid * 8], 16, 0, 0);
    __syncthreads();
    v8bf16 af[4], bf[4];
#pragma unroll
    for (int i = 0; i < 4; i++)
      af[i] = *(const v8bf16*)&As[(wr * 64 + i * 16 + l15) * 32 + quad * 8];
#pragma unroll
    for (int j = 0; j < 4; j++)
      bf[j] = *(const v8bf16*)&Bs[(wc * 64 + j * 16 + l15) * 32 + quad * 8];
#pragma unroll
    for (int i = 0; i < 4; i++)
#pragma unroll
      for (int j = 0; j < 4; j++)
        acc[i][j] = __builtin_amdgcn_mfma_f32_16x16x32_bf16(af[i], bf[j], acc[i][j], 0, 0, 0);
  }
#pragma unroll
  for (int i = 0; i < 4; i++) {
    int rbase = m0 + wr * 64 + i * 16 + quad * 4;
#pragma unroll
    for (int j = 0; j < 4; j++) {
      int col = n0 + wc * 64 + j * 16 + l15;
#pragma unroll
      for (int r = 0; r < 4; r++) {
        float v = acc[i][j][r];
        int row = rbase + r;
        if (mode == 0) {
          outb[(size_t)row * 512 + col] = f2bf(v);
        } else {
          int b2 = row >> 12, mr = row & 4095;
          int kk = mr + 1, kt = kk >> 6, kl = kk & 63;
          int kvsel = col >> 9, hh = (col >> 6) & 7, d = col & 63;
          size_t tb = ((size_t)(b2 * 8 + hh) * 66 + kt) * 8192;
          if (kvsel == 0) {
            int chunk = (((d >> 4) * 2 + ((d >> 3) & 1)) * 2 + (kl >> 5)) * 32 + (kl & 31);
            KVt[tb + (size_t)chunk * 8 + (d & 7)] = f2bf(v * QKS);
          } else {
            int chunk = (((kl >> 4) * 2 + ((kl >> 3) & 1)) * 2 + (d >> 5)) * 32 + (d & 31);
            KVt[tb + 4096 + (size_t)chunk * 8 + (kl & 7)] = f2bf(v);
          }
        }
      }
    }
  }
}

// q-proj (blocks 0..255) and kv-proj (blocks 256..767) in ONE launch: 3 blocks/CU
__global__ __launch_bounds__(256) void gemm_qkv(const u16* __restrict__ xn,
    const u16* __restrict__ WqT, u16* __restrict__ qb,
    const u16* __restrict__ cb, const u16* __restrict__ WkvT,
    u16* __restrict__ KVt) {
  __shared__ __attribute__((aligned(16))) u16 As[128 * 32];
  __shared__ __attribute__((aligned(16))) u16 Bs[128 * 32];
  int bb = blockIdx.x;
  if (bb < 256) gemm_core(xn, WqT, qb, nullptr, 512, 0, bb, As, Bs);
  else          gemm_core(cb, WkvT, nullptr, KVt, 1024, 1, bb - 256, As, Bs);
}

// ---------------- flash attention v16: R8 body + s_setprio around MFMA clusters ----
// S=2, 512 blocks, (256,2), XCD swizzle, exppack2 — all R8-proven. Single delta:
// setprio(1) during MFMA clusters (runtime wave arbitration; no code motion).
__global__ __launch_bounds__(256, 2) void attn_kernel(const u16* __restrict__ q,
    const u16* __restrict__ KVt, const float* __restrict__ maskbias,
    u32* __restrict__ Opart, float* __restrict__ lbuf) {
  int obid = blockIdx.x;
  int bid = (obid & 7) * 64 + (obid >> 3);   // 512 = 8 XCDs * 64: bijective
  int qt = bid & 15, bhs = bid >> 4;
  int s_p = bhs & 1, bh = bhs >> 1;
  int b = bh >> 3, hh = bh & 7;
  int tid = threadIdx.x, lane = tid & 63, w = tid >> 6;
  int m31 = lane & 31, h = (lane >> 5) & 1;
  int grp = (bh * 16 + qt) * 4 + w;
  int q0 = qt * 256 + w * 64;

  // Q B-frags for both 32-row groups: lane col = q0 + qg*32 + m31, k = ks*16+h*8
  v8bf16 qf[2][4];
#pragma unroll
  for (int qg = 0; qg < 2; qg++) {
    const u16* qp = q + (size_t)(b * 4096 + q0 + qg * 32 + m31) * 512 + hh * 64 + h * 8;
#pragma unroll
    for (int ks = 0; ks < 4; ks++) qf[qg][ks] = *(const v8bf16*)&qp[ks * 16];
  }

  v16f32 acc[2][2];
#pragma unroll
  for (int qg = 0; qg < 2; qg++)
#pragma unroll
    for (int db = 0; db < 2; db++)
#pragma unroll
      for (int i = 0; i < 16; i++) acc[qg][db][i] = 0.f;
  float l_st[2] = {0.f, 0.f};

  // lane-fixed base into KVt: + (h*64 + m31)*8 u16
  const u16* kvb = KVt + (size_t)bh * 66 * 8192 + (size_t)(h * 64 + m31) * 8;
  const float* mg = maskbias + b * MPAD;
  int kt0 = s_p * 33;

  for (int kt = kt0; kt < kt0 + 33; ++kt) {
    const u16* tb = kvb + (size_t)kt * 8192;
    // K frags: ks(4) x kc(2), each 16B: offset ks*1024 + kc*256 u16
    v8bf16 kf[4][2];
#pragma unroll
    for (int ks = 0; ks < 4; ks++)
#pragma unroll
      for (int kc = 0; kc < 2; kc++)
        kf[ks][kc] = *(const v8bf16*)&tb[ks * 1024 + kc * 256];
    // bias (C-init values), reused by both q-groups
    v16f32 bias_s[2];
#pragma unroll
    for (int kc = 0; kc < 2; kc++)
#pragma unroll
      for (int gg = 0; gg < 4; gg++) {
        float4 bv = *(const float4*)&mg[kt * 64 + kc * 32 + gg * 8 + h * 4];
        bias_s[kc][gg * 4 + 0] = bv.x;
        bias_s[kc][gg * 4 + 1] = bv.y;
        bias_s[kc][gg * 4 + 2] = bv.z;
        bias_s[kc][gg * 4 + 3] = bv.w;
      }

    v8bf16 pf[2][4];
    // ---- q-group 0: copy bias into s, QK, exp+pack
    {
      v16f32 s0 = bias_s[0], s1 = bias_s[1];
      __builtin_amdgcn_s_setprio(1);
#pragma unroll
      for (int ks = 0; ks < 4; ks++) {
        s0 = __builtin_amdgcn_mfma_f32_32x32x16_bf16(kf[ks][0], qf[0][ks], s0, 0, 0, 0);
        s1 = __builtin_amdgcn_mfma_f32_32x32x16_bf16(kf[ks][1], qf[0][ks], s1, 0, 0, 0);
      }
      __builtin_amdgcn_s_setprio(0);
      exppack2(s0, s1, l_st[0], pf[0]);
    }
    // ---- q-group 1: accumulate INTO the bias registers (saves a copy + regs)
    __builtin_amdgcn_s_setprio(1);
#pragma unroll
    for (int ks = 0; ks < 4; ks++) {
      bias_s[0] = __builtin_amdgcn_mfma_f32_32x32x16_bf16(kf[ks][0], qf[1][ks], bias_s[0], 0, 0, 0);
      bias_s[1] = __builtin_amdgcn_mfma_f32_32x32x16_bf16(kf[ks][1], qf[1][ks], bias_s[1], 0, 0, 0);
    }
    __builtin_amdgcn_s_setprio(0);
    exppack2(bias_s[0], bias_s[1], l_st[1], pf[1]);

    // V frags: jb(4) x db(2) at u16 offset 4096 + jb*1024 + db*256 (K regs now dead)
    v8bf16 vf[4][2];
#pragma unroll
    for (int jb = 0; jb < 4; jb++)
#pragma unroll
      for (int db = 0; db < 2; db++)
        vf[jb][db] = *(const v8bf16*)&tb[4096 + jb * 1024 + db * 256];

    // O^T += V^T * P^T for both q-groups
    __builtin_amdgcn_s_setprio(1);
#pragma unroll
    for (int qg = 0; qg < 2; qg++)
#pragma unroll
      for (int jb = 0; jb < 4; jb++)
#pragma unroll
        for (int db = 0; db < 2; db++)
          acc[qg][db] = __builtin_amdgcn_mfma_f32_32x32x16_bf16(vf[jb][db], pf[qg][jb], acc[qg][db], 0, 0, 0);
    __builtin_amdgcn_s_setprio(0);
  }

  // epilogue: dump raw accumulator (bf16-packed) + l
  size_t ob = (size_t)(s_p * GRPS + grp) * 2048;
#pragma unroll
  for (int qg = 0; qg < 2; qg++)
#pragma unroll
    for (int db = 0; db < 2; db++)
#pragma unroll
      for (int rp = 0; rp < 8; rp++)
        Opart[ob + qg * 1024 + (size_t)(db * 8 + rp) * 64 + lane] =
            pkbf(acc[qg][db][2 * rp], acc[qg][db][2 * rp + 1]);
  if (h == 0) {
    lbuf[(size_t)(s_p * GRPS + grp) * 64 + m31] = l_st[0];
    lbuf[(size_t)(s_p * GRPS + grp) * 64 + 32 + m31] = l_st[1];
  }
}

// ============ tail_fused (cooperative, 512 blocks): combine -> o-proj -> final LN ===
// stage 1: combine 2 partials -> aO (512 blocks, as before)
// stage 2: o-proj GEMM, R0-proven 128x64 tile (512 blocks = 2/CU, was 256 = 1/CU)
// stage 3: final layernorm OP -> out (512 blocks x 16 rows)
// grid.sync() between stages replaces 2 kernel launches (~8 us each).
__global__ __launch_bounds__(256) void tail_fused(const u32* __restrict__ Opart,
    const float* __restrict__ lbuf, u16* __restrict__ attnO,
    const u16* __restrict__ WoT, float* __restrict__ OP,
    const float* __restrict__ g, float* __restrict__ out) {
  __shared__ __attribute__((aligned(16))) unsigned char smem[17408];
  cg::grid_group grid = cg::this_grid();
  int tid = threadIdx.x;

  // ---------------- stage 1: combine ----------------
  {
    u16 (*tl)[2176] = (u16(*)[2176])smem;
    int lane = tid & 63, w4 = tid >> 6;
    int m31 = lane & 31, h = (lane >> 5) & 1;
    int gq = blockIdx.x * 4 + w4;        // 0..2047 = (grp, qg)
    int qg = gq & 1, grp = gq >> 1;
    int w = grp & 3, qt = (grp >> 2) & 15, bh = grp >> 6;
    int b = bh >> 3, hh = bh & 7;

    float l0 = lbuf[(size_t)grp * 64 + qg * 32 + m31];
    float l1 = lbuf[(size_t)(GRPS + grp) * 64 + qg * 32 + m31];
    float inv = 1.f / (l0 + l1);

#pragma unroll
    for (int db = 0; db < 2; db++)
#pragma unroll
      for (int rp = 0; rp < 8; rp++) {
        u32 a = Opart[(size_t)grp * 2048 + qg * 1024 + (db * 8 + rp) * 64 + lane];
        u32 c = Opart[(size_t)(GRPS + grp) * 2048 + qg * 1024 + (db * 8 + rp) * 64 + lane];
        float fe = (asf(a << 16) + asf(c << 16)) * inv;
        float fo = (asf(a & 0xFFFF0000u) + asf(c & 0xFFFF0000u)) * inv;
        int reg = 2 * rp;
        int d0 = (reg & 3) + 8 * (reg >> 2) + 4 * h + 32 * db;
        *(u32*)&tl[w4][m31 * 68 + d0] = pkbf(fe, fo);
      }
    __builtin_amdgcn_s_waitcnt(0);  // wave-private LDS round-trip
    int q0 = qt * 256 + w * 64 + qg * 32;
#pragma unroll
    for (int t2 = 0; t2 < 4; t2++) {
      int row = t2 * 8 + (lane >> 3), ch = lane & 7;
      uint4 val = *(uint4*)&tl[w4][row * 68 + ch * 8];
      *(uint4*)&attnO[(size_t)(b * 4096 + q0 + row) * 512 + hh * 64 + ch * 8] = val;
    }
  }
  __threadfence();
  grid.sync();

  // ---------------- stage 2: o-proj GEMM 128x64 tile (R0-proven body) ----------------
  {
    u16* As = (u16*)smem;               // 128*32 u16 = 8 KB
    u16* Bs = (u16*)(smem + 8192);      //  64*32 u16 = 4 KB
    int bidx = blockIdx.x;
    int n0 = (bidx & 7) * 64;           // 512/64 = 8 n-tiles
    int m0 = (bidx >> 3) * 128;         // 64 m-tiles
    int lane = tid & 63, w = tid >> 6, quad = lane >> 4, l15 = lane & 15;
    int srow = tid >> 2, scol = (tid & 3) * 8;
    v4f32 acc[2][4];
#pragma unroll
    for (int i = 0; i < 2; i++)
#pragma unroll
      for (int j = 0; j < 4; j++) acc[i][j] = (v4f32){0.f, 0.f, 0.f, 0.f};

    for (int k0 = 0; k0 < 512; k0 += 32) {
      __syncthreads();
      __builtin_amdgcn_global_load_lds((const u32*)&attnO[(size_t)(m0 + srow) * 512 + k0 + scol],
                                       (u32*)&As[tid * 8], 16, 0, 0);
      __builtin_amdgcn_global_load_lds((const u32*)&attnO[(size_t)(m0 + 64 + srow) * 512 + k0 + scol],
                                       (u32*)&As[64 * 32 + tid * 8], 16, 0, 0);
      __builtin_amdgcn_global_load_lds((const u32*)&WoT[(size_t)(n0 + srow) * 512 + k0 + scol],
                                       (u32*)&Bs[tid * 8], 16, 0, 0);
      __syncthreads();
      v8bf16 af[2], bf[4];
#pragma unroll
      for (int i = 0; i < 2; i++)
        af[i] = *(const v8bf16*)&As[(w * 32 + i * 16 + l15) * 32 + quad * 8];
#pragma unroll
      for (int j = 0; j < 4; j++)
        bf[j] = *(const v8bf16*)&Bs[(j * 16 + l15) * 32 + quad * 8];
#pragma unroll
      for (int i = 0; i < 2; i++)
#pragma unroll
        for (int j = 0; j < 4; j++)
          acc[i][j] = __builtin_amdgcn_mfma_f32_16x16x32_bf16(af[i], bf[j], acc[i][j], 0, 0, 0);
    }
#pragma unroll
    for (int i = 0; i < 2; i++) {
      int rbase = m0 + w * 32 + i * 16 + quad * 4;
#pragma unroll
      for (int j = 0; j < 4; j++) {
        int col = n0 + j * 16 + l15;
#pragma unroll
        for (int r = 0; r < 4; r++)
          OP[(size_t)(rbase + r) * 512 + col] = acc[i][j][r];
      }
    }
  }
  __threadfence();
  grid.sync();

  // ---------------- stage 3: final layernorm (16 rows/block) ----------------
  {
    int lane = tid & 63, w = tid >> 6;
#pragma unroll
    for (int it = 0; it < 4; it++) {
      int row = blockIdx.x * 16 + it * 4 + w;
      const float* p = OP + (size_t)row * 512 + lane * 8;
      float4 f0 = *(const float4*)p;
      float4 f1 = *(const float4*)(p + 4);
      float v[8] = {f0.x, f0.y, f0.z, f0.w, f1.x, f1.y, f1.z, f1.w};
      float sum = 0.f, sq = 0.f;
#pragma unroll
      for (int i = 0; i < 8; i++) { sum += v[i]; sq += v[i] * v[i]; }
#pragma unroll
      for (int m = 1; m < 64; m <<= 1) { sum += __shfl_xor(sum, m); sq += __shfl_xor(sq, m); }
      float mean = sum * (1.f / 512.f);
      float var = sq * (1.f / 512.f) - mean * mean;
      float rstd = rsqrtf(var + 1e-5f);
      const float* gp = g + lane * 8;
      float o[8];
#pragma unroll
      for (int i = 0; i < 8; i++) o[i] = (v[i] - mean) * rstd * gp[i];
      float* qp = out + (size_t)row * 512 + lane * 8;
      *(float4*)qp = make_float4(o[0], o[1], o[2], o[3]);
      *(float4*)(qp + 4) = make_float4(o[4], o[5], o[6], o[7]);
    }
  }
}

// =======================================================================
extern "C" void kernel_launch(void* const* d_in, const int* in_sizes, int n_in,
                              void* d_out, int out_size, void* d_ws, size_t ws_size,
                              hipStream_t stream) {
  const float* x       = (const float*)d_in[0];
  const float* context = (const float*)d_in[1];
  const void*  mask    = d_in[2];
  const float* g_x     = (const float*)d_in[3];
  const float* null_kv = (const float*)d_in[4];
  const float* Wq      = (const float*)d_in[5];
  const float* Wkv     = (const float*)d_in[6];
  const float* Wo      = (const float*)d_in[7];
  const float* g_out   = (const float*)d_in[8];

  char* w = (char*)d_ws;
  size_t off = 0;
  auto alloc = [&](size_t bytes) { size_t o = off; off = (off + bytes + 255) & ~(size_t)255; return o; };

  u16* WqT    = (u16*)(w + alloc((size_t)512 * 512 * 2));
  u16* WkvT   = (u16*)(w + alloc((size_t)1024 * 512 * 2));
  u16* WoT    = (u16*)(w + alloc((size_t)512 * 512 * 2));
  float* mp   = (float*)(w + alloc((size_t)2 * MPAD * 4));
  u16* KVt    = (u16*)(w + alloc((size_t)16 * 66 * 8192 * 2));
  u16* qb     = (u16*)(w + alloc((size_t)8192 * 512 * 2));
  u16* aO     = (u16*)(w + alloc((size_t)8192 * 512 * 2));
  size_t xn_off = alloc((size_t)8192 * 512 * 2);   // 8 MB
  size_t cb_off = alloc((size_t)8192 * 512 * 2);   // 8 MB (contiguous with xn)
  float* lbb  = (float*)(w + alloc((size_t)2 * GRPS * 64 * 4));
  u16* xn   = (u16*)(w + xn_off);
  u16* cb   = (u16*)(w + cb_off);
  // Opart (2*1024*2048 u32 = 16.78 MB) aliases xn+cb exactly (dead after proj GEMMs)
  u32* Opart = (u32*)(w + xn_off);
  float* OP  = (float*)(w + xn_off);  // fp32 16 MB, used after combine (Opart dead)

  // prep: maskpad | W transposes | ln(x)+cast(ctx) | KVt fill — one launch
  prep_all<<<7217, 256, 0, stream>>>(mask, mp, Wq, Wkv, Wo, WqT, WkvT, WoT,
                                     x, g_x, xn, (const float4*)context, cb,
                                     null_kv, KVt);

  // q-proj + kv-proj in one launch (768 blocks = 3/CU)
  gemm_qkv<<<768, 256, 0, stream>>>(xn, WqT, qb, cb, WkvT, KVt);

  // barrier-free split-K flash attention (S=2)
  attn_kernel<<<512, 256, 0, stream>>>(qb, KVt, mp, Opart, lbb);

  // cooperative tail: combine -> o-proj -> final LN (one launch, grid.sync'd)
  float* outp = (float*)d_out;
  void* args[] = {(void*)&Opart, (void*)&lbb, (void*)&aO, (void*)&WoT,
                  (void*)&OP, (void*)&g_out, (void*)&outp};
  hipLaunchCooperativeKernel((const void*)tail_fused, dim3(512), dim3(256),
                             args, 0, stream);
}

// Round 10
// 232.846 us; speedup vs baseline: 2.0690x; 2.0690x over previous
//
#include <hip/hip_runtime.h>
#include <cfloat>

typedef unsigned short u16;
typedef unsigned int u32;
typedef __bf16 v8bf16 __attribute__((ext_vector_type(8)));
typedef float v4f32 __attribute__((ext_vector_type(4)));
typedef float v16f32 __attribute__((ext_vector_type(16)));

#define MPAD 4224            // 4097 keys padded to 66*64
// sqrt(1/8) * sqrt(log2(e)) : folds head-scale AND base-2 softmax into q and k
#define QKS 0.42466090f
#define GRPS 1024            // waves per split: (16 bh) * (16 qt) * (4 w)

__device__ __forceinline__ u16 f2bf(float f) {
  union { float f; u32 u; } v; v.f = f;
  u32 u = v.u;
  u32 r = (u + 0x7FFFu + ((u >> 16) & 1u)) >> 16;
  return (u16)r;
}

// pack two f32 -> one u32 holding (bf16(hi)<<16)|bf16(lo), truncating
__device__ __forceinline__ u32 pkbf(float lo, float hi) {
  union { float f; u32 u; } a, c;
  a.f = lo; c.f = hi;
  return __builtin_amdgcn_perm(c.u, a.u, 0x07060302);
}

__device__ __forceinline__ float asf(u32 u) {
  union { u32 u; float f; } v; v.u = u; return v.f;
}

// exp2 + row-sum + bf16 pack for one q-group (both kc halves).
// Half-wave exchange via v_permlane32_swap_b32 (R1/R8-proven).
__device__ __forceinline__ void exppack2(v16f32& sA, v16f32& sB, float& lst,
                                         v8bf16 pf[4]) {
  float rsum = 0.f;
#pragma unroll
  for (int i = 0; i < 16; i++) { float p = __builtin_amdgcn_exp2f(sA[i]); sA[i] = p; rsum += p; }
#pragma unroll
  for (int i = 0; i < 16; i++) { float p = __builtin_amdgcn_exp2f(sB[i]); sB[i] = p; rsum += p; }
  float a2 = rsum, b2 = rsum;
  asm("v_permlane32_swap_b32 %0, %1" : "+v"(a2), "+v"(b2));
  lst += a2 + b2;   // own + partner (lane^32)
#pragma unroll
  for (int kc = 0; kc < 2; kc++) {
    v16f32& s = kc ? sB : sA;
#pragma unroll
    for (int s16 = 0; s16 < 2; s16++) {
      u32 w0 = pkbf(s[s16 * 8 + 0], s[s16 * 8 + 1]);
      u32 w1 = pkbf(s[s16 * 8 + 2], s[s16 * 8 + 3]);
      u32 w2 = pkbf(s[s16 * 8 + 4], s[s16 * 8 + 5]);
      u32 w3 = pkbf(s[s16 * 8 + 6], s[s16 * 8 + 7]);
      asm("v_permlane32_swap_b32 %0, %1" : "+v"(w0), "+v"(w2));
      asm("v_permlane32_swap_b32 %0, %1" : "+v"(w1), "+v"(w3));
      union { u32 u[4]; v8bf16 v; } pu;
      pu.u[0] = w0; pu.u[1] = w1; pu.u[2] = w2; pu.u[3] = w3;
      pf[kc * 2 + s16] = pu.v;
    }
  }
}

// ================= prep_all: 4 independent prep stages in ONE launch ===============
// blocks [0,33): mask bias  | [33,1057): W transposes | [1057,7201): ln(x)+cast(ctx)
// | [7201,7217): KVt null-row/pad-tile fill.  All stages mutually independent.
__global__ __launch_bounds__(256) void prep_all(
    const void* __restrict__ mask, float* __restrict__ mp,
    const float* __restrict__ Wq, const float* __restrict__ Wkv,
    const float* __restrict__ Wo, u16* __restrict__ WqT,
    u16* __restrict__ WkvT, u16* __restrict__ WoT,
    const float* __restrict__ x, const float* __restrict__ g,
    u16* __restrict__ xn, const float4* __restrict__ ctx, u16* __restrict__ cb,
    const float* __restrict__ nullkv, u16* __restrict__ KVt) {
  int bb = blockIdx.x;
  int tid = threadIdx.x;
  if (bb < 33) {
    // ---- mask bias build (dtype detect folded in: per-block 8KB scan)
    __shared__ int sflag;
    if (tid == 0) sflag = 0;
    __syncthreads();
    const unsigned char* mb = (const unsigned char*)mask;
    int loc = 0;
#pragma unroll
    for (int k = 0; k < 32; k++) {
      int i = tid * 32 + k;
      if ((i & 3) && mb[i]) loc = 1;
    }
    if (loc) sflag = 1;
    __syncthreads();
    int isbyte = sflag;
    int i = bb * 256 + tid;
    if (i >= 2 * MPAD) return;
    int b = i / MPAD, p = i - b * MPAD;
    float v;
    if (p == 0) v = 0.f;
    else if (p <= 4096) {
      int j = b * 4096 + (p - 1);
      int on = isbyte ? (((const unsigned char*)mask)[j] != 0)
                      : (((const int*)mask)[j] != 0);
      v = on ? 0.f : -1e38f;
    } else v = -1e38f;
    mp[i] = v;
  } else if (bb < 1057) {
    // ---- fused transpose of Wq/Wkv/Wo fp32 [K][N] -> bf16 [N][K]
    __shared__ float tile[32][33];
    int t = bb - 33;
    const float* in; u16* out; int N; float scale; int base;
    if (t < 256)      { in = Wq;  out = WqT;  N = 512;  scale = QKS; base = t; }
    else if (t < 768) { in = Wkv; out = WkvT; N = 1024; scale = 1.f; base = t - 256; }
    else              { in = Wo;  out = WoT;  N = 512;  scale = 1.f; base = t - 768; }
    const int K = 512;
    int ntiles = N >> 5;
    int bx = base % ntiles, by = base / ntiles;
    int n0 = bx * 32, k0 = by * 32;
    int c = tid & 31, r8 = tid >> 5;
#pragma unroll
    for (int i = 0; i < 4; i++) {
      int r = r8 + i * 8;
      tile[r][c] = in[(size_t)(k0 + r) * N + n0 + c];
    }
    __syncthreads();
#pragma unroll
    for (int i = 0; i < 4; i++) {
      int r = r8 + i * 8;
      out[(size_t)(n0 + r) * K + k0 + c] = f2bf(tile[c][r] * scale);
    }
  } else if (bb < 7201) {
    int local = bb - 1057;
    if (local < 2048) {
      // ---- layernorm(x) row(512) -> bf16
      int lane = tid & 63, w = tid >> 6;
      int row = local * 4 + w;
      const float* p = x + (size_t)row * 512 + lane * 8;
      float4 f0 = *(const float4*)p;
      float4 f1 = *(const float4*)(p + 4);
      float v[8] = {f0.x, f0.y, f0.z, f0.w, f1.x, f1.y, f1.z, f1.w};
      float sum = 0.f, sq = 0.f;
#pragma unroll
      for (int i = 0; i < 8; i++) { sum += v[i]; sq += v[i] * v[i]; }
#pragma unroll
      for (int m = 1; m < 64; m <<= 1) { sum += __shfl_xor(sum, m); sq += __shfl_xor(sq, m); }
      float mean = sum * (1.f / 512.f);
      float var = sq * (1.f / 512.f) - mean * mean;
      float rstd = rsqrtf(var + 1e-5f);
      const float* gp = g + lane * 8;
      u16 o[8];
#pragma unroll
      for (int i = 0; i < 8; i++) o[i] = f2bf((v[i] - mean) * rstd * gp[i]);
      *(uint4*)&xn[(size_t)row * 512 + lane * 8] = *(uint4*)o;
    } else {
      // ---- cast context fp32 -> bf16
      int i = (local - 2048) * 256 + tid;
      float4 f = ctx[i];
      u16 o[4] = {f2bf(f.x), f2bf(f.y), f2bf(f.z), f2bf(f.w)};
      *(uint2*)&cb[(size_t)i * 4] = *(uint2*)o;
    }
  } else {
    // ---- KVt: zero pad tiles 64/65, write null row kk=0
    int bh = bb - 7201;
    size_t tb64 = ((size_t)bh * 66 + 64) * 8192;
    uint4 z = make_uint4(0, 0, 0, 0);
    for (int i = tid; i < 2048; i += 256)
      *(uint4*)&KVt[tb64 + (size_t)i * 8] = z;
    size_t tb0 = (size_t)bh * 66 * 8192;
    if (tid < 64) {
      int d = tid;
      KVt[tb0 + (size_t)(d >> 3) * 512 + (d & 7)] = f2bf(nullkv[d] * QKS);
      KVt[tb0 + 4096 + (size_t)d * 8] = f2bf(nullkv[64 + d]);
    }
  }
}

// ---------------- layernorm fp32 row(512) -> fp32 (final) ----------------
__global__ __launch_bounds__(256) void ln_to_f32(const float* __restrict__ in,
    const float* __restrict__ g, float* __restrict__ out) {
  int lane = threadIdx.x & 63, w = threadIdx.x >> 6;
  int row = blockIdx.x * 4 + w;
  const float* p = in + (size_t)row * 512 + lane * 8;
  float4 f0 = *(const float4*)p;
  float4 f1 = *(const float4*)(p + 4);
  float v[8] = {f0.x, f0.y, f0.z, f0.w, f1.x, f1.y, f1.z, f1.w};
  float sum = 0.f, sq = 0.f;
#pragma unroll
  for (int i = 0; i < 8; i++) { sum += v[i]; sq += v[i] * v[i]; }
#pragma unroll
  for (int m = 1; m < 64; m <<= 1) { sum += __shfl_xor(sum, m); sq += __shfl_xor(sq, m); }
  float mean = sum * (1.f / 512.f);
  float var = sq * (1.f / 512.f) - mean * mean;
  float rstd = rsqrtf(var + 1e-5f);
  const float* gp = g + lane * 8;
  float o[8];
#pragma unroll
  for (int i = 0; i < 8; i++) o[i] = (v[i] - mean) * rstd * gp[i];
  float* q = out + (size_t)row * 512 + lane * 8;
  *(float4*)q = make_float4(o[0], o[1], o[2], o[3]);
  *(float4*)(q + 4) = make_float4(o[4], o[5], o[6], o[7]);
}

// ---------------- bf16 MFMA GEMM core: C[M x N] = A[M x 512] * Bt[N x 512]^T -------
// m97-structure: 128x128 tile, 256 thr (4 waves as 2x2, each 64x64, 4x4 acc)
// mode 0: out bf16 row-major [M][512]; mode 1: scatter to KVt frag-layout
__device__ __forceinline__ void gemm_core(const u16* __restrict__ A,
    const u16* __restrict__ Bt, u16* __restrict__ outb,
    u16* __restrict__ KVt, int Ncols, int mode, int bidx,
    u16* As /*128*32*/, u16* Bs /*128*32*/) {
  int tiles_n = Ncols >> 7;
  int n0 = (bidx % tiles_n) * 128;
  int m0 = (bidx / tiles_n) * 128;
  int tid = threadIdx.x;
  int lane = tid & 63, w = tid >> 6, quad = lane >> 4, l15 = lane & 15;
  int wr = w >> 1, wc = w & 1;
  int srow = tid >> 2, scol = (tid & 3) * 8;
  v4f32 acc[4][4];
#pragma unroll
  for (int i = 0; i < 4; i++)
#pragma unroll
    for (int j = 0; j < 4; j++) acc[i][j] = (v4f32){0.f, 0.f, 0.f, 0.f};

  for (int k0 = 0; k0 < 512; k0 += 32) {
    __syncthreads();
    __builtin_amdgcn_global_load_lds((const u32*)&A[(size_t)(m0 + srow) * 512 + k0 + scol],
                                     (u32*)&As[tid * 8], 16, 0, 0);
    __builtin_amdgcn_global_load_lds((const u32*)&A[(size_t)(m0 + 64 + srow) * 512 + k0 + scol],
                                     (u32*)&As[64 * 32 + tid * 8], 16, 0, 0);
    __builtin_amdgcn_global_load_lds((const u32*)&Bt[(size_t)(n0 + srow) * 512 + k0 + scol],
                                     (u32*)&Bs[tid * 8], 16, 0, 0);
    __builtin_amdgcn_global_load_lds((const u32*)&Bt[(size_t)(n0 + 64 + srow) * 512 + k0 + scol],
                                     (u32*)&Bs[64 * 32 + tid * 8], 16, 0, 0);
    __syncthreads();
    v8bf16 af[4], bf[4];
#pragma unroll
    for (int i = 0; i < 4; i++)
      af[i] = *(const v8bf16*)&As[(wr * 64 + i * 16 + l15) * 32 + quad * 8];
#pragma unroll
    for (int j = 0; j < 4; j++)
      bf[j] = *(const v8bf16*)&Bs[(wc * 64 + j * 16 + l15) * 32 + quad * 8];
#pragma unroll
    for (int i = 0; i < 4; i++)
#pragma unroll
      for (int j = 0; j < 4; j++)
        acc[i][j] = __builtin_amdgcn_mfma_f32_16x16x32_bf16(af[i], bf[j], acc[i][j], 0, 0, 0);
  }
#pragma unroll
  for (int i = 0; i < 4; i++) {
    int rbase = m0 + wr * 64 + i * 16 + quad * 4;
#pragma unroll
    for (int j = 0; j < 4; j++) {
      int col = n0 + wc * 64 + j * 16 + l15;
#pragma unroll
      for (int r = 0; r < 4; r++) {
        float v = acc[i][j][r];
        int row = rbase + r;
        if (mode == 0) {
          outb[(size_t)row * 512 + col] = f2bf(v);
        } else {
          int b2 = row >> 12, mr = row & 4095;
          int kk = mr + 1, kt = kk >> 6, kl = kk & 63;
          int kvsel = col >> 9, hh = (col >> 6) & 7, d = col & 63;
          size_t tb = ((size_t)(b2 * 8 + hh) * 66 + kt) * 8192;
          if (kvsel == 0) {
            int chunk = (((d >> 4) * 2 + ((d >> 3) & 1)) * 2 + (kl >> 5)) * 32 + (kl & 31);
            KVt[tb + (size_t)chunk * 8 + (d & 7)] = f2bf(v * QKS);
          } else {
            int chunk = (((kl >> 4) * 2 + ((kl >> 3) & 1)) * 2 + (d >> 5)) * 32 + (d & 31);
            KVt[tb + 4096 + (size_t)chunk * 8 + (kl & 7)] = f2bf(v);
          }
        }
      }
    }
  }
}

// q-proj (blocks 0..255) and kv-proj (blocks 256..767) in ONE launch: 3 blocks/CU
__global__ __launch_bounds__(256) void gemm_qkv(const u16* __restrict__ xn,
    const u16* __restrict__ WqT, u16* __restrict__ qb,
    const u16* __restrict__ cb, const u16* __restrict__ WkvT,
    u16* __restrict__ KVt) {
  __shared__ __attribute__((aligned(16))) u16 As[128 * 32];
  __shared__ __attribute__((aligned(16))) u16 Bs[128 * 32];
  int bb = blockIdx.x;
  if (bb < 256) gemm_core(xn, WqT, qb, nullptr, 512, 0, bb, As, Bs);
  else          gemm_core(cb, WkvT, nullptr, KVt, 1024, 1, bb - 256, As, Bs);
}

// ---------------- o-proj: 128x64 tile (R0-proven body), 512 blocks = 2/CU ----------
__global__ __launch_bounds__(256) void gemm_o(const u16* __restrict__ A,
    const u16* __restrict__ Bt, float* __restrict__ outf) {
  __shared__ __attribute__((aligned(16))) u16 As[128 * 32];
  __shared__ __attribute__((aligned(16))) u16 Bs[64 * 32];
  int n0 = (blockIdx.x & 7) * 64;      // 512/64 = 8 n-tiles
  int m0 = (blockIdx.x >> 3) * 128;    // 64 m-tiles
  int tid = threadIdx.x;
  int lane = tid & 63, w = tid >> 6, quad = lane >> 4, l15 = lane & 15;
  int srow = tid >> 2, scol = (tid & 3) * 8;
  v4f32 acc[2][4];
#pragma unroll
  for (int i = 0; i < 2; i++)
#pragma unroll
    for (int j = 0; j < 4; j++) acc[i][j] = (v4f32){0.f, 0.f, 0.f, 0.f};

  for (int k0 = 0; k0 < 512; k0 += 32) {
    __syncthreads();
    __builtin_amdgcn_global_load_lds((const u32*)&A[(size_t)(m0 + srow) * 512 + k0 + scol],
                                     (u32*)&As[tid * 8], 16, 0, 0);
    __builtin_amdgcn_global_load_lds((const u32*)&A[(size_t)(m0 + 64 + srow) * 512 + k0 + scol],
                                     (u32*)&As[64 * 32 + tid * 8], 16, 0, 0);
    __builtin_amdgcn_global_load_lds((const u32*)&Bt[(size_t)(n0 + srow) * 512 + k0 + scol],
                                     (u32*)&Bs[tid * 8], 16, 0, 0);
    __syncthreads();
    v8bf16 af[2], bf[4];
#pragma unroll
    for (int i = 0; i < 2; i++)
      af[i] = *(const v8bf16*)&As[(w * 32 + i * 16 + l15) * 32 + quad * 8];
#pragma unroll
    for (int j = 0; j < 4; j++)
      bf[j] = *(const v8bf16*)&Bs[(j * 16 + l15) * 32 + quad * 8];
#pragma unroll
    for (int i = 0; i < 2; i++)
#pragma unroll
      for (int j = 0; j < 4; j++)
        acc[i][j] = __builtin_amdgcn_mfma_f32_16x16x32_bf16(af[i], bf[j], acc[i][j], 0, 0, 0);
  }
#pragma unroll
  for (int i = 0; i < 2; i++) {
    int rbase = m0 + w * 32 + i * 16 + quad * 4;
#pragma unroll
    for (int j = 0; j < 4; j++) {
      int col = n0 + j * 16 + l15;
#pragma unroll
      for (int r = 0; r < 4; r++)
        outf[(size_t)(rbase + r) * 512 + col] = acc[i][j][r];
    }
  }
}

// ---------------- flash attention v16: R8 body + s_setprio around MFMA clusters ----
// S=2, 512 blocks, (256,2), XCD swizzle, exppack2 — all R8-proven. setprio kept
// from R9 (untested there: tail noise); this round gives its clean A/B vs 102.2.
__global__ __launch_bounds__(256, 2) void attn_kernel(const u16* __restrict__ q,
    const u16* __restrict__ KVt, const float* __restrict__ maskbias,
    u32* __restrict__ Opart, float* __restrict__ lbuf) {
  int obid = blockIdx.x;
  int bid = (obid & 7) * 64 + (obid >> 3);   // 512 = 8 XCDs * 64: bijective
  int qt = bid & 15, bhs = bid >> 4;
  int s_p = bhs & 1, bh = bhs >> 1;
  int b = bh >> 3, hh = bh & 7;
  int tid = threadIdx.x, lane = tid & 63, w = tid >> 6;
  int m31 = lane & 31, h = (lane >> 5) & 1;
  int grp = (bh * 16 + qt) * 4 + w;
  int q0 = qt * 256 + w * 64;

  // Q B-frags for both 32-row groups: lane col = q0 + qg*32 + m31, k = ks*16+h*8
  v8bf16 qf[2][4];
#pragma unroll
  for (int qg = 0; qg < 2; qg++) {
    const u16* qp = q + (size_t)(b * 4096 + q0 + qg * 32 + m31) * 512 + hh * 64 + h * 8;
#pragma unroll
    for (int ks = 0; ks < 4; ks++) qf[qg][ks] = *(const v8bf16*)&qp[ks * 16];
  }

  v16f32 acc[2][2];
#pragma unroll
  for (int qg = 0; qg < 2; qg++)
#pragma unroll
    for (int db = 0; db < 2; db++)
#pragma unroll
      for (int i = 0; i < 16; i++) acc[qg][db][i] = 0.f;
  float l_st[2] = {0.f, 0.f};

  // lane-fixed base into KVt: + (h*64 + m31)*8 u16
  const u16* kvb = KVt + (size_t)bh * 66 * 8192 + (size_t)(h * 64 + m31) * 8;
  const float* mg = maskbias + b * MPAD;
  int kt0 = s_p * 33;

  for (int kt = kt0; kt < kt0 + 33; ++kt) {
    const u16* tb = kvb + (size_t)kt * 8192;
    // K frags: ks(4) x kc(2), each 16B: offset ks*1024 + kc*256 u16
    v8bf16 kf[4][2];
#pragma unroll
    for (int ks = 0; ks < 4; ks++)
#pragma unroll
      for (int kc = 0; kc < 2; kc++)
        kf[ks][kc] = *(const v8bf16*)&tb[ks * 1024 + kc * 256];
    // bias (C-init values), reused by both q-groups
    v16f32 bias_s[2];
#pragma unroll
    for (int kc = 0; kc < 2; kc++)
#pragma unroll
      for (int gg = 0; gg < 4; gg++) {
        float4 bv = *(const float4*)&mg[kt * 64 + kc * 32 + gg * 8 + h * 4];
        bias_s[kc][gg * 4 + 0] = bv.x;
        bias_s[kc][gg * 4 + 1] = bv.y;
        bias_s[kc][gg * 4 + 2] = bv.z;
        bias_s[kc][gg * 4 + 3] = bv.w;
      }

    v8bf16 pf[2][4];
    // ---- q-group 0: copy bias into s, QK, exp+pack
    {
      v16f32 s0 = bias_s[0], s1 = bias_s[1];
      __builtin_amdgcn_s_setprio(1);
#pragma unroll
      for (int ks = 0; ks < 4; ks++) {
        s0 = __builtin_amdgcn_mfma_f32_32x32x16_bf16(kf[ks][0], qf[0][ks], s0, 0, 0, 0);
        s1 = __builtin_amdgcn_mfma_f32_32x32x16_bf16(kf[ks][1], qf[0][ks], s1, 0, 0, 0);
      }
      __builtin_amdgcn_s_setprio(0);
      exppack2(s0, s1, l_st[0], pf[0]);
    }
    // ---- q-group 1: accumulate INTO the bias registers (saves a copy + regs)
    __builtin_amdgcn_s_setprio(1);
#pragma unroll
    for (int ks = 0; ks < 4; ks++) {
      bias_s[0] = __builtin_amdgcn_mfma_f32_32x32x16_bf16(kf[ks][0], qf[1][ks], bias_s[0], 0, 0, 0);
      bias_s[1] = __builtin_amdgcn_mfma_f32_32x32x16_bf16(kf[ks][1], qf[1][ks], bias_s[1], 0, 0, 0);
    }
    __builtin_amdgcn_s_setprio(0);
    exppack2(bias_s[0], bias_s[1], l_st[1], pf[1]);

    // V frags: jb(4) x db(2) at u16 offset 4096 + jb*1024 + db*256 (K regs now dead)
    v8bf16 vf[4][2];
#pragma unroll
    for (int jb = 0; jb < 4; jb++)
#pragma unroll
      for (int db = 0; db < 2; db++)
        vf[jb][db] = *(const v8bf16*)&tb[4096 + jb * 1024 + db * 256];

    // O^T += V^T * P^T for both q-groups
    __builtin_amdgcn_s_setprio(1);
#pragma unroll
    for (int qg = 0; qg < 2; qg++)
#pragma unroll
      for (int jb = 0; jb < 4; jb++)
#pragma unroll
        for (int db = 0; db < 2; db++)
          acc[qg][db] = __builtin_amdgcn_mfma_f32_32x32x16_bf16(vf[jb][db], pf[qg][jb], acc[qg][db], 0, 0, 0);
    __builtin_amdgcn_s_setprio(0);
  }

  // epilogue: dump raw accumulator (bf16-packed) + l
  size_t ob = (size_t)(s_p * GRPS + grp) * 2048;
#pragma unroll
  for (int qg = 0; qg < 2; qg++)
#pragma unroll
    for (int db = 0; db < 2; db++)
#pragma unroll
      for (int rp = 0; rp < 8; rp++)
        Opart[ob + qg * 1024 + (size_t)(db * 8 + rp) * 64 + lane] =
            pkbf(acc[qg][db][2 * rp], acc[qg][db][2 * rp + 1]);
  if (h == 0) {
    lbuf[(size_t)(s_p * GRPS + grp) * 64 + m31] = l_st[0];
    lbuf[(size_t)(s_p * GRPS + grp) * 64 + 32 + m31] = l_st[1];
  }
}

// ---------------- combine 2 partials -> attnO (bf16 [row][512]) ----------------
__global__ __launch_bounds__(256) void attn_combine(const u32* __restrict__ Opart,
    const float* __restrict__ lbuf, u16* __restrict__ attnO) {
  __shared__ __attribute__((aligned(16))) u16 tl[4][2176];
  int tid = threadIdx.x, lane = tid & 63, w4 = tid >> 6;
  int m31 = lane & 31, h = (lane >> 5) & 1;
  int gq = blockIdx.x * 4 + w4;        // 0..2047 = (grp, qg)
  int qg = gq & 1, grp = gq >> 1;
  int w = grp & 3, qt = (grp >> 2) & 15, bh = grp >> 6;
  int b = bh >> 3, hh = bh & 7;

  float l0 = lbuf[(size_t)grp * 64 + qg * 32 + m31];
  float l1 = lbuf[(size_t)(GRPS + grp) * 64 + qg * 32 + m31];
  float inv = 1.f / (l0 + l1);

#pragma unroll
  for (int db = 0; db < 2; db++)
#pragma unroll
    for (int rp = 0; rp < 8; rp++) {
      u32 a = Opart[(size_t)grp * 2048 + qg * 1024 + (db * 8 + rp) * 64 + lane];
      u32 c = Opart[(size_t)(GRPS + grp) * 2048 + qg * 1024 + (db * 8 + rp) * 64 + lane];
      float fe = (asf(a << 16) + asf(c << 16)) * inv;
      float fo = (asf(a & 0xFFFF0000u) + asf(c & 0xFFFF0000u)) * inv;
      int reg = 2 * rp;
      int d0 = (reg & 3) + 8 * (reg >> 2) + 4 * h + 32 * db;
      *(u32*)&tl[w4][m31 * 68 + d0] = pkbf(fe, fo);
    }
  __builtin_amdgcn_s_waitcnt(0);  // wave-private LDS round-trip
  int q0 = qt * 256 + w * 64 + qg * 32;
#pragma unroll
  for (int t2 = 0; t2 < 4; t2++) {
    int row = t2 * 8 + (lane >> 3), ch = lane & 7;
    uint4 val = *(uint4*)&tl[w4][row * 68 + ch * 8];
    *(uint4*)&attnO[(size_t)(b * 4096 + q0 + row) * 512 + hh * 64 + ch * 8] = val;
  }
}

// =======================================================================
extern "C" void kernel_launch(void* const* d_in, const int* in_sizes, int n_in,
                              void* d_out, int out_size, void* d_ws, size_t ws_size,
                              hipStream_t stream) {
  const float* x       = (const float*)d_in[0];
  const float* context = (const float*)d_in[1];
  const void*  mask    = d_in[2];
  const float* g_x     = (const float*)d_in[3];
  const float* null_kv = (const float*)d_in[4];
  const float* Wq      = (const float*)d_in[5];
  const float* Wkv     = (const float*)d_in[6];
  const float* Wo      = (const float*)d_in[7];
  const float* g_out   = (const float*)d_in[8];

  char* w = (char*)d_ws;
  size_t off = 0;
  auto alloc = [&](size_t bytes) { size_t o = off; off = (off + bytes + 255) & ~(size_t)255; return o; };

  u16* WqT    = (u16*)(w + alloc((size_t)512 * 512 * 2));
  u16* WkvT   = (u16*)(w + alloc((size_t)1024 * 512 * 2));
  u16* WoT    = (u16*)(w + alloc((size_t)512 * 512 * 2));
  float* mp   = (float*)(w + alloc((size_t)2 * MPAD * 4));
  u16* KVt    = (u16*)(w + alloc((size_t)16 * 66 * 8192 * 2));
  u16* qb     = (u16*)(w + alloc((size_t)8192 * 512 * 2));
  u16* aO     = (u16*)(w + alloc((size_t)8192 * 512 * 2));
  size_t xn_off = alloc((size_t)8192 * 512 * 2);   // 8 MB
  size_t cb_off = alloc((size_t)8192 * 512 * 2);   // 8 MB (contiguous with xn)
  float* lbb  = (float*)(w + alloc((size_t)2 * GRPS * 64 * 4));
  u16* xn   = (u16*)(w + xn_off);
  u16* cb   = (u16*)(w + cb_off);
  // Opart (2*1024*2048 u32 = 16.78 MB) aliases xn+cb exactly (dead after proj GEMMs)
  u32* Opart = (u32*)(w + xn_off);
  float* OP  = (float*)(w + xn_off);  // fp32 16 MB, used after combine (Opart dead)

  // prep: maskpad | W transposes | ln(x)+cast(ctx) | KVt fill — one launch
  prep_all<<<7217, 256, 0, stream>>>(mask, mp, Wq, Wkv, Wo, WqT, WkvT, WoT,
                                     x, g_x, xn, (const float4*)context, cb,
                                     null_kv, KVt);

  // q-proj + kv-proj in one launch (768 blocks = 3/CU)
  gemm_qkv<<<768, 256, 0, stream>>>(xn, WqT, qb, cb, WkvT, KVt);

  // barrier-free split-K flash attention (S=2) + combine
  attn_kernel<<<512, 256, 0, stream>>>(qb, KVt, mp, Opart, lbb);
  attn_combine<<<512, 256, 0, stream>>>(Opart, lbb, aO);

  // out = attnO @ Wo -> fp32 (128x64 tile, 512 blocks = 2/CU), then final LN
  gemm_o<<<512, 256, 0, stream>>>(aO, WoT, OP);
  ln_to_f32<<<2048, 256, 0, stream>>>(OP, g_out, (float*)d_out);
}